// Round 1
// baseline (820.180 us; speedup 1.0000x reference)
//
#include <hip/hip_runtime.h>
#include <hip/hip_bf16.h>
#include <stdint.h>

#define NT   16384   // tokens = B*S
#define C_   768
#define DFF_ 3072
#define KX   3072    // N*C
#define NMIX 24

typedef __attribute__((ext_vector_type(8))) short shortx8;
typedef __attribute__((ext_vector_type(4))) float floatx4;

__device__ __forceinline__ short f2bf(float f) {
  union { float f; uint32_t u; } v; v.f = f;
  uint32_t r = v.u + 0x7fffu + ((v.u >> 16) & 1u);   // RNE
  return (short)(r >> 16);
}

// ---------- prep: phi (3072x24) -> phiT (24x3072) fp32 ----------
__global__ void phiT_kernel(const float* __restrict__ phi, float* __restrict__ phiT) {
  int idx = blockIdx.x * 256 + threadIdx.x;
  if (idx < KX * NMIX) {
    int k = idx / NMIX, j = idx - k * NMIX;
    phiT[(size_t)j * KX + k] = phi[idx];
  }
}

// ---------- prep: fp32 (R x C) -> bf16 transposed (C x R) ----------
__global__ __launch_bounds__(256) void transpose_bf16(const float* __restrict__ in,
                                                      short* __restrict__ out,
                                                      int R, int C) {
  __shared__ float tile[32][33];
  int bx = blockIdx.x * 32;   // C dim
  int by = blockIdx.y * 32;   // R dim
  int tx = threadIdx.x & 31, ty = threadIdx.x >> 5;
  #pragma unroll
  for (int i = 0; i < 32; i += 8)
    tile[ty + i][tx] = in[(size_t)(by + ty + i) * C + bx + tx];
  __syncthreads();
  #pragma unroll
  for (int i = 0; i < 32; i += 8)
    out[(size_t)(bx + ty + i) * R + by + tx] = f2bf(tile[tx][ty + i]);
}

// ---------- k1: per-token mix / sinkhorn / h_pre / h_post / x_in ----------
#define TB 64
__global__ __launch_bounds__(256) void k1(
    const float* __restrict__ x, const float* __restrict__ phiT,
    const float* __restrict__ bvec, const float* __restrict__ a_pre,
    const float* __restrict__ a_post, const float* __restrict__ a_res,
    short* __restrict__ x_in, float* __restrict__ hpost, float* __restrict__ hres) {
  __shared__ float xs[TB][132];     // 128-k chunk, +4 pad (16B-aligned rows)
  __shared__ float invr_s[TB];
  __shared__ float mixs[TB][NMIX];
  __shared__ float hpre_s[TB][4];
  int tid = threadIdx.x;
  int lane = tid & 63;              // token within block
  int w = tid >> 6;                 // j-group (6 j's per wave)
  int wu = __builtin_amdgcn_readfirstlane(w);
  int t0 = blockIdx.x * TB;

  float acc[6] = {0.f, 0.f, 0.f, 0.f, 0.f, 0.f};
  float ssq = 0.f;

  for (int kc = 0; kc < KX; kc += 128) {
    if (kc) __syncthreads();
    #pragma unroll
    for (int jj = 0; jj < 8; ++jj) {          // stage 64 tokens x 128 k
      int idx = tid + jj * 256;
      int row = idx >> 5, c4 = idx & 31;
      const float4 v = *(const float4*)&x[(size_t)(t0 + row) * KX + kc + c4 * 4];
      *(float4*)&xs[row][c4 * 4] = v;
    }
    __syncthreads();
    #pragma unroll 4
    for (int k4 = 0; k4 < 32; ++k4) {
      const float4 xv = *(const float4*)&xs[lane][k4 * 4];
      if (w == 0) ssq += xv.x * xv.x + xv.y * xv.y + xv.z * xv.z + xv.w * xv.w;
      int kk = kc + k4 * 4;
      #pragma unroll
      for (int jj = 0; jj < 6; ++jj) {        // phi via wave-uniform (scalar) loads
        const float4 p = *(const float4*)&phiT[(size_t)(wu * 6 + jj) * KX + kk];
        acc[jj] += p.x * xv.x + p.y * xv.y + p.z * xv.z + p.w * xv.w;
      }
    }
  }
  if (w == 0) invr_s[lane] = rsqrtf(ssq * (1.0f / KX) + 1e-6f);
  #pragma unroll
  for (int jj = 0; jj < 6; ++jj) mixs[lane][w * 6 + jj] = acc[jj];
  __syncthreads();

  {  // sinkhorn: thread = (token tq, row r); cols in regs, col-sums via shfl
    int tq = tid >> 2, r = tid & 3;
    float invr = invr_s[tq];
    float ares = a_res[0];
    float v0 = mixs[tq][8 + r * 4 + 0] * invr * ares + bvec[8 + r * 4 + 0];
    float v1 = mixs[tq][8 + r * 4 + 1] * invr * ares + bvec[8 + r * 4 + 1];
    float v2 = mixs[tq][8 + r * 4 + 2] * invr * ares + bvec[8 + r * 4 + 2];
    float v3 = mixs[tq][8 + r * 4 + 3] * invr * ares + bvec[8 + r * 4 + 3];
    float mx = fmaxf(fmaxf(v0, v1), fmaxf(v2, v3));
    v0 = __expf(v0 - mx); v1 = __expf(v1 - mx); v2 = __expf(v2 - mx); v3 = __expf(v3 - mx);
    for (int it = 0; it < 20; ++it) {
      float s = v0 + v1 + v2 + v3 + 1e-6f;    // row normalize (ref adds eps to sum)
      float inv = 1.0f / s;
      v0 *= inv; v1 *= inv; v2 *= inv; v3 *= inv;
      float c0 = v0 + __shfl_xor(v0, 1); c0 += __shfl_xor(c0, 2);
      float c1 = v1 + __shfl_xor(v1, 1); c1 += __shfl_xor(c1, 2);
      float c2 = v2 + __shfl_xor(v2, 1); c2 += __shfl_xor(c2, 2);
      float c3 = v3 + __shfl_xor(v3, 1); c3 += __shfl_xor(c3, 2);
      v0 /= (c0 + 1e-6f); v1 /= (c1 + 1e-6f); v2 /= (c2 + 1e-6f); v3 /= (c3 + 1e-6f);
    }
    float* ho = hres + (size_t)(t0 + tq) * 16 + r * 4;
    ho[0] = v0; ho[1] = v1; ho[2] = v2; ho[3] = v3;
    if (r == 0) {
      float apre = a_pre[0];
      #pragma unroll
      for (int n = 0; n < 4; ++n) {
        float z = mixs[tq][n] * invr * apre + bvec[n];
        hpre_s[tq][n] = 1.0f / (1.0f + __expf(-z));
      }
    } else if (r == 1) {
      float apost = a_post[0];
      #pragma unroll
      for (int n = 0; n < 4; ++n) {
        float z = mixs[tq][4 + n] * invr * apost + bvec[4 + n];
        hpost[(size_t)(t0 + tq) * 4 + n] = 2.0f / (1.0f + __expf(-z));
      }
    }
  }
  __syncthreads();

  // x_in[t][c] = sum_n h_pre[n] * x[t][n*768+c], stored bf16 (rows are L2-warm)
  if (tid < 192) {
    int c = tid * 4;
    for (int t = 0; t < TB; ++t) {
      const float* xr = x + (size_t)(t0 + t) * KX + c;
      float4 x0 = *(const float4*)(xr);
      float4 x1 = *(const float4*)(xr + C_);
      float4 x2 = *(const float4*)(xr + 2 * C_);
      float4 x3 = *(const float4*)(xr + 3 * C_);
      float p0 = hpre_s[t][0], p1 = hpre_s[t][1], p2 = hpre_s[t][2], p3 = hpre_s[t][3];
      short4 s;
      s.x = f2bf(p0 * x0.x + p1 * x1.x + p2 * x2.x + p3 * x3.x);
      s.y = f2bf(p0 * x0.y + p1 * x1.y + p2 * x2.y + p3 * x3.y);
      s.z = f2bf(p0 * x0.z + p1 * x1.z + p2 * x2.z + p3 * x3.z);
      s.w = f2bf(p0 * x0.w + p1 * x1.w + p2 * x2.w + p3 * x3.w);
      *(short4*)&x_in[(size_t)(t0 + t) * C_ + c] = s;
    }
  }
}

// ---------- m97-style bf16 GEMM, B^T input, fused epilogues ----------
// EPI=1: out_bf16 = gelu(A@B^T + bias)            (act for the 2nd GEMM)
// EPI=2: out_f32[t,n,:] = hres@x + hpost*(A@B^T + bias)   (final output)
template <int EPI>
__global__ __launch_bounds__(256, 3) void gemm_bt(
    const short* __restrict__ A, const short* __restrict__ B,
    int M, int N, int K, const float* __restrict__ bias,
    short* __restrict__ outb,
    const float* __restrict__ x, const float* __restrict__ hres,
    const float* __restrict__ hpost, float* __restrict__ out) {
  __shared__ short As[128 * 32];
  __shared__ short Bs[128 * 32];
  int tid = threadIdx.x;
  int lane = tid & 63, w = tid >> 6;
  int m0 = blockIdx.y * 128, n0 = blockIdx.x * 128;
  int wm = (w >> 1) * 64, wn = (w & 1) * 64;
  int lrow = lane & 15, quad = lane >> 4;
  floatx4 acc[4][4] = {};

  for (int k0 = 0; k0 < K; k0 += 32) {
    if (k0) __syncthreads();
    #pragma unroll
    for (int i = 0; i < 2; ++i) {
      int c = tid + i * 256;
      int row = c >> 2, slot = c & 3;
      const short* ga = A + (size_t)(m0 + row) * K + k0 + slot * 8;
      const short* gb = B + (size_t)(n0 + row) * K + k0 + slot * 8;
      __builtin_amdgcn_global_load_lds((const __attribute__((address_space(1))) void*)ga,
                                       (__attribute__((address_space(3))) void*)&As[c * 8],
                                       16, 0, 0);
      __builtin_amdgcn_global_load_lds((const __attribute__((address_space(1))) void*)gb,
                                       (__attribute__((address_space(3))) void*)&Bs[c * 8],
                                       16, 0, 0);
    }
    __syncthreads();
    shortx8 af[4], bfr[4];
    #pragma unroll
    for (int mi = 0; mi < 4; ++mi)
      af[mi] = *(const shortx8*)&As[(wm + mi * 16 + lrow) * 32 + quad * 8];
    #pragma unroll
    for (int ni = 0; ni < 4; ++ni)
      bfr[ni] = *(const shortx8*)&Bs[(wn + ni * 16 + lrow) * 32 + quad * 8];
    #pragma unroll
    for (int mi = 0; mi < 4; ++mi)
      #pragma unroll
      for (int ni = 0; ni < 4; ++ni)
        acc[mi][ni] = __builtin_amdgcn_mfma_f32_16x16x32_bf16(af[mi], bfr[ni], acc[mi][ni], 0, 0, 0);
  }

  float bcol[4];
  #pragma unroll
  for (int ni = 0; ni < 4; ++ni) bcol[ni] = bias[n0 + wn + ni * 16 + lrow];

  if (EPI == 1) {
    #pragma unroll
    for (int mi = 0; mi < 4; ++mi) {
      #pragma unroll
      for (int r = 0; r < 4; ++r) {
        int row = m0 + wm + mi * 16 + quad * 4 + r;
        #pragma unroll
        for (int ni = 0; ni < 4; ++ni) {
          int col = n0 + wn + ni * 16 + lrow;
          float v = acc[mi][ni][r] + bcol[ni];
          float g = 0.5f * v * (1.0f + erff(v * 0.70710678118654752f));  // exact gelu
          outb[(size_t)row * N + col] = f2bf(g);
        }
      }
    }
  } else {
    #pragma unroll
    for (int mi = 0; mi < 4; ++mi) {
      #pragma unroll
      for (int r = 0; r < 4; ++r) {
        int row = m0 + wm + mi * 16 + quad * 4 + r;
        const float* hr = hres + (size_t)row * 16;
        const float* hp = hpost + (size_t)row * 4;
        const float* xr = x + (size_t)row * KX;
        float* orow = out + (size_t)row * KX;
        float hrv[16];
        #pragma unroll
        for (int q = 0; q < 16; ++q) hrv[q] = hr[q];
        float h0 = hp[0], h1 = hp[1], h2 = hp[2], h3 = hp[3];
        #pragma unroll
        for (int ni = 0; ni < 4; ++ni) {
          int col = n0 + wn + ni * 16 + lrow;
          float f = acc[mi][ni][r] + bcol[ni];
          float x0 = xr[col], x1 = xr[C_ + col], x2 = xr[2 * C_ + col], x3 = xr[3 * C_ + col];
          orow[col]            = hrv[0] * x0 + hrv[1] * x1 + hrv[2] * x2 + hrv[3] * x3 + h0 * f;
          orow[C_ + col]       = hrv[4] * x0 + hrv[5] * x1 + hrv[6] * x2 + hrv[7] * x3 + h1 * f;
          orow[2 * C_ + col]   = hrv[8] * x0 + hrv[9] * x1 + hrv[10] * x2 + hrv[11] * x3 + h2 * f;
          orow[3 * C_ + col]   = hrv[12] * x0 + hrv[13] * x1 + hrv[14] * x2 + hrv[15] * x3 + h3 * f;
        }
      }
    }
  }
}

extern "C" void kernel_launch(void* const* d_in, const int* in_sizes, int n_in,
                              void* d_out, int out_size, void* d_ws, size_t ws_size,
                              hipStream_t stream) {
  const float* x      = (const float*)d_in[0];
  const float* phi    = (const float*)d_in[1];
  const float* b      = (const float*)d_in[2];
  const float* a_pre  = (const float*)d_in[3];
  const float* a_post = (const float*)d_in[4];
  const float* a_res  = (const float*)d_in[5];
  const float* W1     = (const float*)d_in[6];
  const float* b1     = (const float*)d_in[7];
  const float* W2     = (const float*)d_in[8];
  const float* b2     = (const float*)d_in[9];
  float* out = (float*)d_out;

  char* ws = (char*)d_ws;
  size_t off = 0;
  auto carve = [&](size_t bytes) {
    char* p = ws + off;
    off += (bytes + 255) & ~(size_t)255;
    return p;
  };
  short* x_in  = (short*)carve((size_t)NT * C_ * 2);        //  25.2 MB bf16
  short* act   = (short*)carve((size_t)NT * DFF_ * 2);      // 100.7 MB bf16
  float* hpost = (float*)carve((size_t)NT * 4 * 4);
  float* hres  = (float*)carve((size_t)NT * 16 * 4);
  short* W1T   = (short*)carve((size_t)DFF_ * C_ * 2);
  short* W2T   = (short*)carve((size_t)C_ * DFF_ * 2);
  float* phiT  = (float*)carve((size_t)NMIX * KX * 4);

  phiT_kernel<<<dim3((KX * NMIX + 255) / 256), 256, 0, stream>>>(phi, phiT);
  transpose_bf16<<<dim3(DFF_ / 32, C_ / 32), 256, 0, stream>>>(W1, W1T, C_, DFF_);
  transpose_bf16<<<dim3(C_ / 32, DFF_ / 32), 256, 0, stream>>>(W2, W2T, DFF_, C_);
  k1<<<dim3(NT / TB), 256, 0, stream>>>(x, phiT, b, a_pre, a_post, a_res, x_in, hpost, hres);
  gemm_bt<1><<<dim3(DFF_ / 128, NT / 128), 256, 0, stream>>>(
      x_in, W1T, NT, DFF_, C_, b1, act, nullptr, nullptr, nullptr, nullptr);
  gemm_bt<2><<<dim3(C_ / 128, NT / 128), 256, 0, stream>>>(
      act, W2T, NT, C_, DFF_, b2, nullptr, x, hres, hpost, out);
}

// Round 2
// 717.291 us; speedup vs baseline: 1.1434x; 1.1434x over previous
//
#include <hip/hip_runtime.h>
#include <hip/hip_bf16.h>
#include <stdint.h>

#define NT   16384   // tokens = B*S
#define C_   768
#define DFF_ 3072
#define KX   3072    // N*C
#define NMIX 24
#define TB   64
#define KSPLIT 4
#define KSEG (KX / KSPLIT)   // 768

typedef __attribute__((ext_vector_type(8))) short shortx8;
typedef __attribute__((ext_vector_type(4))) float floatx4;

__device__ __forceinline__ short f2bf(float f) {
  union { float f; uint32_t u; } v; v.f = f;
  uint32_t r = v.u + 0x7fffu + ((v.u >> 16) & 1u);   // RNE
  return (short)(r >> 16);
}

// ---------- prep: phi (3072x24) -> phiT (24x3072) fp32 ----------
__global__ void phiT_kernel(const float* __restrict__ phi, float* __restrict__ phiT) {
  int idx = blockIdx.x * 256 + threadIdx.x;
  if (idx < KX * NMIX) {
    int k = idx / NMIX, j = idx - k * NMIX;
    phiT[(size_t)j * KX + k] = phi[idx];
  }
}

// ---------- prep: fp32 (R x C) -> bf16 transposed (C x R) ----------
__global__ __launch_bounds__(256) void transpose_bf16(const float* __restrict__ in,
                                                      short* __restrict__ out,
                                                      int R, int C) {
  __shared__ float tile[32][33];
  int bx = blockIdx.x * 32;   // C dim
  int by = blockIdx.y * 32;   // R dim
  int tx = threadIdx.x & 31, ty = threadIdx.x >> 5;
  #pragma unroll
  for (int i = 0; i < 32; i += 8)
    tile[ty + i][tx] = in[(size_t)(by + ty + i) * C + bx + tx];
  __syncthreads();
  #pragma unroll
  for (int i = 0; i < 32; i += 8)
    out[(size_t)(bx + ty + i) * R + by + tx] = f2bf(tile[tx][ty + i]);
}

// ---------- k1a: partial mix + partial ssq over a 768-wide k segment ----------
// grid = (NT/TB) * KSPLIT blocks; block handles 64 tokens x 768 k
__global__ __launch_bounds__(256) void k1a(
    const float* __restrict__ x, const float* __restrict__ phiT,
    float* __restrict__ pmix, float* __restrict__ pssq) {
  __shared__ float xs[TB][132];     // 128-k chunk, +4 pad
  int tid = threadIdx.x;
  int lane = tid & 63;              // token within block
  int w = tid >> 6;                 // j-group (6 j's per wave)
  int wu = __builtin_amdgcn_readfirstlane(w);
  int t0 = (blockIdx.x >> 2) * TB;
  int slot = blockIdx.x & 3;
  int ks = slot * KSEG;

  float acc[6] = {0.f, 0.f, 0.f, 0.f, 0.f, 0.f};
  float ssq = 0.f;

  for (int kc = ks; kc < ks + KSEG; kc += 128) {
    if (kc != ks) __syncthreads();
    #pragma unroll
    for (int jj = 0; jj < 8; ++jj) {          // stage 64 tokens x 128 k
      int idx = tid + jj * 256;
      int row = idx >> 5, c4 = idx & 31;
      const float4 v = *(const float4*)&x[(size_t)(t0 + row) * KX + kc + c4 * 4];
      *(float4*)&xs[row][c4 * 4] = v;
    }
    __syncthreads();
    #pragma unroll 4
    for (int k4 = 0; k4 < 32; ++k4) {
      const float4 xv = *(const float4*)&xs[lane][k4 * 4];
      if (w == 0) ssq += xv.x * xv.x + xv.y * xv.y + xv.z * xv.z + xv.w * xv.w;
      int kk = kc + k4 * 4;
      #pragma unroll
      for (int jj = 0; jj < 6; ++jj) {        // phi via wave-uniform (scalar) loads
        const float4 p = *(const float4*)&phiT[(size_t)(wu * 6 + jj) * KX + kk];
        acc[jj] += p.x * xv.x + p.y * xv.y + p.z * xv.z + p.w * xv.w;
      }
    }
  }
  if (w == 0) pssq[(size_t)(t0 + lane) * KSPLIT + slot] = ssq;
  #pragma unroll
  for (int jj = 0; jj < 6; ++jj)
    pmix[((size_t)(t0 + lane) * KSPLIT + slot) * NMIX + wu * 6 + jj] = acc[jj];
}

// ---------- k1b: reduce partials + sinkhorn + h_pre/h_post/h_res ----------
__global__ __launch_bounds__(256) void k1b(
    const float* __restrict__ pmix, const float* __restrict__ pssq,
    const float* __restrict__ bvec, const float* __restrict__ a_pre,
    const float* __restrict__ a_post, const float* __restrict__ a_res,
    float* __restrict__ hpre, float* __restrict__ hpost, float* __restrict__ hres) {
  __shared__ float mixs[TB][NMIX];
  __shared__ float invr_s[TB];
  int tid = threadIdx.x;
  int t0 = blockIdx.x * TB;
  int tq = tid >> 2, r = tid & 3;

  {   // thread (tq, r) reduces j-range [r*6, r*6+6) over 4 k-slots
    const float* pm = pmix + (size_t)(t0 + tq) * KSPLIT * NMIX;
    float s[6] = {0.f, 0.f, 0.f, 0.f, 0.f, 0.f};
    #pragma unroll
    for (int sl = 0; sl < KSPLIT; ++sl)
      #pragma unroll
      for (int jj = 0; jj < 6; ++jj)
        s[jj] += pm[sl * NMIX + r * 6 + jj];
    #pragma unroll
    for (int jj = 0; jj < 6; ++jj) mixs[tq][r * 6 + jj] = s[jj];
    if (r == 0) {
      const float* ps = pssq + (size_t)(t0 + tq) * KSPLIT;
      float sq = ps[0] + ps[1] + ps[2] + ps[3];
      invr_s[tq] = rsqrtf(sq * (1.0f / KX) + 1e-6f);
    }
  }
  __syncthreads();

  {  // sinkhorn: thread = (token tq, row r); cols in regs, col-sums via shfl
    float invr = invr_s[tq];
    float ares = a_res[0];
    float v0 = mixs[tq][8 + r * 4 + 0] * invr * ares + bvec[8 + r * 4 + 0];
    float v1 = mixs[tq][8 + r * 4 + 1] * invr * ares + bvec[8 + r * 4 + 1];
    float v2 = mixs[tq][8 + r * 4 + 2] * invr * ares + bvec[8 + r * 4 + 2];
    float v3 = mixs[tq][8 + r * 4 + 3] * invr * ares + bvec[8 + r * 4 + 3];
    float mx = fmaxf(fmaxf(v0, v1), fmaxf(v2, v3));
    v0 = __expf(v0 - mx); v1 = __expf(v1 - mx); v2 = __expf(v2 - mx); v3 = __expf(v3 - mx);
    for (int it = 0; it < 20; ++it) {
      float s = v0 + v1 + v2 + v3 + 1e-6f;    // row normalize (ref adds eps to sum)
      float inv = 1.0f / s;
      v0 *= inv; v1 *= inv; v2 *= inv; v3 *= inv;
      float c0 = v0 + __shfl_xor(v0, 1); c0 += __shfl_xor(c0, 2);
      float c1 = v1 + __shfl_xor(v1, 1); c1 += __shfl_xor(c1, 2);
      float c2 = v2 + __shfl_xor(v2, 1); c2 += __shfl_xor(c2, 2);
      float c3 = v3 + __shfl_xor(v3, 1); c3 += __shfl_xor(c3, 2);
      v0 /= (c0 + 1e-6f); v1 /= (c1 + 1e-6f); v2 /= (c2 + 1e-6f); v3 /= (c3 + 1e-6f);
    }
    float* ho = hres + (size_t)(t0 + tq) * 16 + r * 4;
    ho[0] = v0; ho[1] = v1; ho[2] = v2; ho[3] = v3;
    if (r == 0) {
      float apre = a_pre[0];
      float4 hp;
      hp.x = 1.0f / (1.0f + __expf(-(mixs[tq][0] * invr * apre + bvec[0])));
      hp.y = 1.0f / (1.0f + __expf(-(mixs[tq][1] * invr * apre + bvec[1])));
      hp.z = 1.0f / (1.0f + __expf(-(mixs[tq][2] * invr * apre + bvec[2])));
      hp.w = 1.0f / (1.0f + __expf(-(mixs[tq][3] * invr * apre + bvec[3])));
      *(float4*)&hpre[(size_t)(t0 + tq) * 4] = hp;
    } else if (r == 1) {
      float apost = a_post[0];
      float4 hq;
      hq.x = 2.0f / (1.0f + __expf(-(mixs[tq][4] * invr * apost + bvec[4])));
      hq.y = 2.0f / (1.0f + __expf(-(mixs[tq][5] * invr * apost + bvec[5])));
      hq.z = 2.0f / (1.0f + __expf(-(mixs[tq][6] * invr * apost + bvec[6])));
      hq.w = 2.0f / (1.0f + __expf(-(mixs[tq][7] * invr * apost + bvec[7])));
      *(float4*)&hpost[(size_t)(t0 + tq) * 4] = hq;
    }
  }
}

// ---------- k1c: x_in[t][c] = sum_n hpre[t][n] * x[t][n*768+c], bf16 out ----------
// one short4 (4 outputs) per thread; grid = NT*192/256 blocks
__global__ __launch_bounds__(256) void k1c(
    const float* __restrict__ x, const float* __restrict__ hpre,
    short* __restrict__ x_in) {
  int idx = blockIdx.x * 256 + threadIdx.x;   // NT*192 float4-groups
  int t = idx / 192;
  int c = (idx - t * 192) * 4;
  float4 hp = *(const float4*)&hpre[(size_t)t * 4];
  const float* xr = x + (size_t)t * KX + c;
  float4 x0 = *(const float4*)(xr);
  float4 x1 = *(const float4*)(xr + C_);
  float4 x2 = *(const float4*)(xr + 2 * C_);
  float4 x3 = *(const float4*)(xr + 3 * C_);
  short4 s;
  s.x = f2bf(hp.x * x0.x + hp.y * x1.x + hp.z * x2.x + hp.w * x3.x);
  s.y = f2bf(hp.x * x0.y + hp.y * x1.y + hp.z * x2.y + hp.w * x3.y);
  s.z = f2bf(hp.x * x0.z + hp.y * x1.z + hp.z * x2.z + hp.w * x3.z);
  s.w = f2bf(hp.x * x0.w + hp.y * x1.w + hp.z * x2.w + hp.w * x3.w);
  *(short4*)&x_in[(size_t)t * C_ + c] = s;
}

// ---------- m97-style bf16 GEMM, B^T input, fused epilogues ----------
// EPI=1: out_bf16 = gelu(A@B^T + bias)            (act for the 2nd GEMM)
// EPI=2: out_f32[t,n,:] = hres@x + hpost*(A@B^T + bias)   (final output)
template <int EPI>
__global__ __launch_bounds__(256, 3) void gemm_bt(
    const short* __restrict__ A, const short* __restrict__ B,
    int M, int N, int K, const float* __restrict__ bias,
    short* __restrict__ outb,
    const float* __restrict__ x, const float* __restrict__ hres,
    const float* __restrict__ hpost, float* __restrict__ out) {
  __shared__ short As[128 * 32];
  __shared__ short Bs[128 * 32];
  int tid = threadIdx.x;
  int lane = tid & 63, w = tid >> 6;
  int m0 = blockIdx.y * 128, n0 = blockIdx.x * 128;
  int wm = (w >> 1) * 64, wn = (w & 1) * 64;
  int lrow = lane & 15, quad = lane >> 4;
  floatx4 acc[4][4] = {};

  for (int k0 = 0; k0 < K; k0 += 32) {
    if (k0) __syncthreads();
    #pragma unroll
    for (int i = 0; i < 2; ++i) {
      int c = tid + i * 256;
      int row = c >> 2, slot = c & 3;
      const short* ga = A + (size_t)(m0 + row) * K + k0 + slot * 8;
      const short* gb = B + (size_t)(n0 + row) * K + k0 + slot * 8;
      __builtin_amdgcn_global_load_lds((const __attribute__((address_space(1))) void*)ga,
                                       (__attribute__((address_space(3))) void*)&As[c * 8],
                                       16, 0, 0);
      __builtin_amdgcn_global_load_lds((const __attribute__((address_space(1))) void*)gb,
                                       (__attribute__((address_space(3))) void*)&Bs[c * 8],
                                       16, 0, 0);
    }
    __syncthreads();
    shortx8 af[4], bfr[4];
    #pragma unroll
    for (int mi = 0; mi < 4; ++mi)
      af[mi] = *(const shortx8*)&As[(wm + mi * 16 + lrow) * 32 + quad * 8];
    #pragma unroll
    for (int ni = 0; ni < 4; ++ni)
      bfr[ni] = *(const shortx8*)&Bs[(wn + ni * 16 + lrow) * 32 + quad * 8];
    #pragma unroll
    for (int mi = 0; mi < 4; ++mi)
      #pragma unroll
      for (int ni = 0; ni < 4; ++ni)
        acc[mi][ni] = __builtin_amdgcn_mfma_f32_16x16x32_bf16(af[mi], bfr[ni], acc[mi][ni], 0, 0, 0);
  }

  float bcol[4];
  #pragma unroll
  for (int ni = 0; ni < 4; ++ni) bcol[ni] = bias[n0 + wn + ni * 16 + lrow];

  if (EPI == 1) {
    #pragma unroll
    for (int mi = 0; mi < 4; ++mi) {
      #pragma unroll
      for (int r = 0; r < 4; ++r) {
        int row = m0 + wm + mi * 16 + quad * 4 + r;
        #pragma unroll
        for (int ni = 0; ni < 4; ++ni) {
          int col = n0 + wn + ni * 16 + lrow;
          float v = acc[mi][ni][r] + bcol[ni];
          float g = 0.5f * v * (1.0f + erff(v * 0.70710678118654752f));  // exact gelu
          outb[(size_t)row * N + col] = f2bf(g);
        }
      }
    }
  } else {
    #pragma unroll
    for (int mi = 0; mi < 4; ++mi) {
      #pragma unroll
      for (int r = 0; r < 4; ++r) {
        int row = m0 + wm + mi * 16 + quad * 4 + r;
        const float* hr = hres + (size_t)row * 16;
        const float* hp = hpost + (size_t)row * 4;
        const float* xr = x + (size_t)row * KX;
        float* orow = out + (size_t)row * KX;
        float hrv[16];
        #pragma unroll
        for (int q = 0; q < 16; ++q) hrv[q] = hr[q];
        float h0 = hp[0], h1 = hp[1], h2 = hp[2], h3 = hp[3];
        #pragma unroll
        for (int ni = 0; ni < 4; ++ni) {
          int col = n0 + wn + ni * 16 + lrow;
          float f = acc[mi][ni][r] + bcol[ni];
          float x0 = xr[col], x1 = xr[C_ + col], x2 = xr[2 * C_ + col], x3 = xr[3 * C_ + col];
          orow[col]            = hrv[0] * x0 + hrv[1] * x1 + hrv[2] * x2 + hrv[3] * x3 + h0 * f;
          orow[C_ + col]       = hrv[4] * x0 + hrv[5] * x1 + hrv[6] * x2 + hrv[7] * x3 + h1 * f;
          orow[2 * C_ + col]   = hrv[8] * x0 + hrv[9] * x1 + hrv[10] * x2 + hrv[11] * x3 + h2 * f;
          orow[3 * C_ + col]   = hrv[12] * x0 + hrv[13] * x1 + hrv[14] * x2 + hrv[15] * x3 + h3 * f;
        }
      }
    }
  }
}

extern "C" void kernel_launch(void* const* d_in, const int* in_sizes, int n_in,
                              void* d_out, int out_size, void* d_ws, size_t ws_size,
                              hipStream_t stream) {
  const float* x      = (const float*)d_in[0];
  const float* phi    = (const float*)d_in[1];
  const float* b      = (const float*)d_in[2];
  const float* a_pre  = (const float*)d_in[3];
  const float* a_post = (const float*)d_in[4];
  const float* a_res  = (const float*)d_in[5];
  const float* W1     = (const float*)d_in[6];
  const float* b1     = (const float*)d_in[7];
  const float* W2     = (const float*)d_in[8];
  const float* b2     = (const float*)d_in[9];
  float* out = (float*)d_out;

  char* ws = (char*)d_ws;
  size_t off = 0;
  auto carve = [&](size_t bytes) {
    char* p = ws + off;
    off += (bytes + 255) & ~(size_t)255;
    return p;
  };
  short* x_in  = (short*)carve((size_t)NT * C_ * 2);        //  25.2 MB bf16
  short* act   = (short*)carve((size_t)NT * DFF_ * 2);      // 100.7 MB bf16
  float* hpost = (float*)carve((size_t)NT * 4 * 4);
  float* hres  = (float*)carve((size_t)NT * 16 * 4);
  float* hpre  = (float*)carve((size_t)NT * 4 * 4);
  short* W1T   = (short*)carve((size_t)DFF_ * C_ * 2);
  short* W2T   = (short*)carve((size_t)C_ * DFF_ * 2);
  float* phiT  = (float*)carve((size_t)NMIX * KX * 4);
  float* pmix  = (float*)carve((size_t)NT * KSPLIT * NMIX * 4);  // 6.3 MB
  float* pssq  = (float*)carve((size_t)NT * KSPLIT * 4);

  phiT_kernel<<<dim3((KX * NMIX + 255) / 256), 256, 0, stream>>>(phi, phiT);
  transpose_bf16<<<dim3(DFF_ / 32, C_ / 32), 256, 0, stream>>>(W1, W1T, C_, DFF_);
  transpose_bf16<<<dim3(C_ / 32, DFF_ / 32), 256, 0, stream>>>(W2, W2T, DFF_, C_);
  k1a<<<dim3((NT / TB) * KSPLIT), 256, 0, stream>>>(x, phiT, pmix, pssq);
  k1b<<<dim3(NT / TB), 256, 0, stream>>>(pmix, pssq, b, a_pre, a_post, a_res,
                                         hpre, hpost, hres);
  k1c<<<dim3(NT * 192 / 256), 256, 0, stream>>>(x, hpre, x_in);
  gemm_bt<1><<<dim3(DFF_ / 128, NT / 128), 256, 0, stream>>>(
      x_in, W1T, NT, DFF_, C_, b1, act, nullptr, nullptr, nullptr, nullptr);
  gemm_bt<2><<<dim3(C_ / 128, NT / 128), 256, 0, stream>>>(
      act, W2T, NT, C_, DFF_, b2, nullptr, x, hres, hpost, out);
}